// Round 4
// baseline (824.370 us; speedup 1.0000x reference)
//
#include <hip/hip_runtime.h>

#define NN   50000
#define IN_F 128
#define HF   256
#define COUT 64
#define MLPH 128
#define EG   600000
#define EK   800000
#define BN_EPS 1e-5f

typedef __attribute__((ext_vector_type(8))) short short8;
typedef __attribute__((ext_vector_type(8))) unsigned short ushort8;
typedef __attribute__((ext_vector_type(4))) float f32x4;

__device__ __forceinline__ unsigned short f2bf(float f) {
  union { float f; unsigned int u; } v; v.f = f;
  unsigned int r = v.u + 0x7FFFu + ((v.u >> 16) & 1u);
  return (unsigned short)(r >> 16);
}
__device__ __forceinline__ float bf2f(unsigned short s) {
  union { unsigned int u; float f; } v; v.u = ((unsigned int)s) << 16;
  return v.f;
}

// ---------------- feat -> bf16 ----------------
__global__ __launch_bounds__(256) void cvt_bf16_kernel(const float* __restrict__ in,
                                                       unsigned short* __restrict__ out,
                                                       int n8) {
  int i = blockIdx.x * 256 + threadIdx.x;
  if (i < n8) {
    float4 a = *reinterpret_cast<const float4*>(&in[i * 8]);
    float4 b = *reinterpret_cast<const float4*>(&in[i * 8 + 4]);
    ushort8 o;
    o[0] = f2bf(a.x); o[1] = f2bf(a.y); o[2] = f2bf(a.z); o[3] = f2bf(a.w);
    o[4] = f2bf(b.x); o[5] = f2bf(b.y); o[6] = f2bf(b.z); o[7] = f2bf(b.w);
    *reinterpret_cast<ushort8*>(&out[i * 8]) = o;
  }
}

// ---------------- weight transpose+convert ----------------
struct WDesc { const float* src; int rows; int cshift; int kofs; int ldk; int dofs; };
struct WPack { WDesc d[12]; };

__global__ __launch_bounds__(256) void transpose_weights_kernel(WPack p,
                                                                unsigned short* __restrict__ dst) {
  WDesc w = p.d[blockIdx.y];
  int total = w.rows << w.cshift;
  int cmask = (1 << w.cshift) - 1;
  for (int idx = blockIdx.x * 256 + threadIdx.x; idx < total; idx += gridDim.x * 256) {
    int r = idx >> w.cshift;
    int c = idx & cmask;
    dst[w.dofs + (size_t)c * w.ldk + w.kofs + r] = f2bf(w.src[idx]);
  }
}

// ---------------- CSR build ----------------
__global__ __launch_bounds__(256) void count_kernel(const int* __restrict__ dst, int E,
                                                    int* __restrict__ cnt) {
  int e = blockIdx.x * 256 + threadIdx.x;
  if (e < E) atomicAdd(&cnt[dst[e]], 1);
}

__global__ __launch_bounds__(256) void invdeg_kernel(const int* __restrict__ cnt,
                                                     float* __restrict__ inv) {
  int i = blockIdx.x * 256 + threadIdx.x;
  if (i < NN) inv[i] = 1.0f / fmaxf((float)cnt[i], 1.0f);
}

// ---- parallel scan: partials -> scan partials -> per-block scan ----
__global__ __launch_bounds__(256) void scan_partial(const int* __restrict__ cnt,
                                                    int* __restrict__ part, int n) {
  int i = blockIdx.x * 256 + threadIdx.x;
  int v = (i < n) ? cnt[i] : 0;
  __shared__ int ws[4];
  int lane = threadIdx.x & 63, wid = threadIdx.x >> 6;
  int x = v;
#pragma unroll
  for (int d = 1; d < 64; d <<= 1) { int y = __shfl_up(x, d, 64); if (lane >= d) x += y; }
  if (lane == 63) ws[wid] = x;
  __syncthreads();
  if (threadIdx.x == 0) part[blockIdx.x] = ws[0] + ws[1] + ws[2] + ws[3];
}

__global__ __launch_bounds__(256) void scan_block(int* __restrict__ part, int np) {
  __shared__ int ws[4];
  int tid = threadIdx.x, lane = tid & 63, wid = tid >> 6;
  int v = (tid < np) ? part[tid] : 0;
  int x = v;
#pragma unroll
  for (int d = 1; d < 64; d <<= 1) { int y = __shfl_up(x, d, 64); if (lane >= d) x += y; }
  if (lane == 63) ws[wid] = x;
  __syncthreads();
  int add = 0;
#pragma unroll
  for (int k = 0; k < 4; ++k) if (k < wid) add += ws[k];
  if (tid < np) part[tid] = x - v + add;
}

__global__ __launch_bounds__(256) void scan_final(const int* __restrict__ cnt,
                                                  const int* __restrict__ part,
                                                  int* __restrict__ off, int n, int total) {
  int i = blockIdx.x * 256 + threadIdx.x;
  int v = (i < n) ? cnt[i] : 0;
  __shared__ int ws[4];
  int lane = threadIdx.x & 63, wid = threadIdx.x >> 6;
  int x = v;
#pragma unroll
  for (int d = 1; d < 64; d <<= 1) { int y = __shfl_up(x, d, 64); if (lane >= d) x += y; }
  if (lane == 63) ws[wid] = x;
  __syncthreads();
  int add = part[blockIdx.x];
#pragma unroll
  for (int k = 0; k < 4; ++k) if (k < wid) add += ws[k];
  if (i < n) off[i] = x - v + add;
  if (i == 0) off[n] = total;
}

__global__ __launch_bounds__(256) void fill_kernel(const int* __restrict__ src,
                                                   const int* __restrict__ dst, int E,
                                                   const int* __restrict__ off,
                                                   int* __restrict__ cursor,
                                                   int* __restrict__ esrc) {
  int e = blockIdx.x * 256 + threadIdx.x;
  if (e < E) {
    int d = dst[e];
    int p = atomicAdd(&cursor[d], 1);
    esrc[off[d] + p] = src[e];
  }
}

// ---------------- dim-chunked CSR mean-aggregation (bf16 in/out) ----------------
// chunk = blockIdx.x % NCHUNK (-> one 64B dim-slice per XCD, L2-resident slice);
// each 4-lane group owns one node's 32-dim chunk, NPG consecutive nodes per group.
template <int DLOG2, int NCHUNK, int NPG>
__global__ __launch_bounds__(256) void csr_aggregate_chunk(
    const unsigned short* __restrict__ h, const int* __restrict__ off,
    const int* __restrict__ esrc, const float* __restrict__ inv,
    unsigned short* __restrict__ out) {
  static_assert(((1 << DLOG2) / NCHUNK) == 32, "32 dims (64B) per chunk");
  const int chunk = blockIdx.x % NCHUNK;
  const int ng = blockIdx.x / NCHUNK;
  const int group = threadIdx.x >> 2;    // 64 groups/block
  const int lane = threadIdx.x & 3;
  const int dbase = chunk * 32 + lane * 8;
  int node0 = (ng * 64 + group) * NPG;
  if (node0 >= NN) return;
  int node_end = node0 + NPG;
  if (node_end > NN) node_end = NN;
  int s = off[node0];
  for (int node = node0; node < node_end; ++node) {
    int e = off[node + 1];
    float acc[8] = {0.f, 0.f, 0.f, 0.f, 0.f, 0.f, 0.f, 0.f};
    int j = s;
    for (; j + 1 < e; j += 2) {
      int s0 = esrc[j], s1 = esrc[j + 1];
      ushort8 v0 = *reinterpret_cast<const ushort8*>(&h[((size_t)s0 << DLOG2) + dbase]);
      ushort8 v1 = *reinterpret_cast<const ushort8*>(&h[((size_t)s1 << DLOG2) + dbase]);
#pragma unroll
      for (int i = 0; i < 8; ++i) acc[i] += bf2f(v0[i]);
#pragma unroll
      for (int i = 0; i < 8; ++i) acc[i] += bf2f(v1[i]);
    }
    if (j < e) {
      int s0 = esrc[j];
      ushort8 v0 = *reinterpret_cast<const ushort8*>(&h[((size_t)s0 << DLOG2) + dbase]);
#pragma unroll
      for (int i = 0; i < 8; ++i) acc[i] += bf2f(v0[i]);
    }
    float sc = inv[node];
    ushort8 o;
#pragma unroll
    for (int i = 0; i < 8; ++i) o[i] = f2bf(acc[i] * sc);
    *reinterpret_cast<ushort8*>(&out[((size_t)node << DLOG2) + dbase]) = o;
    s = e;
  }
}

// ---------------- MFMA GEMM ----------------
template <int K1, int K2, bool RELU, bool BN1, bool OUT_BF16>
__global__ __launch_bounds__(256) void gemm_mfma(
    const void* __restrict__ A1v, const void* __restrict__ A2v,
    const unsigned short* __restrict__ Bt, const float* __restrict__ bias,
    const float* __restrict__ bnscale, const float* __restrict__ bnshift,
    void* __restrict__ outv, int ldo, int nrows) {
  constexpr int KTOT = K1 + K2;
  constexpr int KT = KTOT / 64;
  constexpr int LDT = 72;
  __shared__ char smem[2 * 64 * LDT * 2];
  unsigned short* As = (unsigned short*)smem;
  unsigned short* Bs = As + 64 * LDT;
  float* Co = (float*)smem;
  constexpr int LDC = 68;

  const int t = threadIdx.x;
  const int lane = t & 63;
  const int w = t >> 6;
  const int wm = (w & 1) * 32, wn = (w >> 1) * 32;
  const int row0 = blockIdx.y * 64;
  const int n0 = blockIdx.x * 64;

  const int sr = t >> 2;
  const int skc = (t & 3) * 16;
  int rg = row0 + sr;
  if (rg >= nrows) rg = nrows - 1;

  f32x4 acc[2][2] = {};

  for (int kt = 0; kt < KT; ++kt) {
    const int kbase = kt * 64;
    if (BN1) {
      const float* xb = (const float*)A1v + (size_t)rg * K1 + kbase + skc;
      ushort8 o0, o1;
#pragma unroll
      for (int i = 0; i < 8; ++i) {
        float v = xb[i] * bnscale[kbase + skc + i] + bnshift[kbase + skc + i];
        o0[i] = f2bf(fmaxf(v, 0.f));
      }
#pragma unroll
      for (int i = 0; i < 8; ++i) {
        float v = xb[8 + i] * bnscale[kbase + skc + 8 + i] + bnshift[kbase + skc + 8 + i];
        o1[i] = f2bf(fmaxf(v, 0.f));
      }
      *reinterpret_cast<ushort8*>(&As[sr * LDT + skc]) = o0;
      *reinterpret_cast<ushort8*>(&As[sr * LDT + skc + 8]) = o1;
    } else {
      const unsigned short* ab;
      if (kbase < K1)
        ab = (const unsigned short*)A1v + (size_t)rg * K1 + kbase + skc;
      else
        ab = (const unsigned short*)A2v + (size_t)rg * K2 + (kbase - K1) + skc;
      int4 p0 = *reinterpret_cast<const int4*>(ab);
      int4 p1 = *reinterpret_cast<const int4*>(ab + 8);
      *reinterpret_cast<int4*>(&As[sr * LDT + skc]) = p0;
      *reinterpret_cast<int4*>(&As[sr * LDT + skc + 8]) = p1;
    }
    {
      const unsigned short* bb = Bt + (size_t)(n0 + sr) * KTOT + kbase + skc;
      int4 p0 = *reinterpret_cast<const int4*>(bb);
      int4 p1 = *reinterpret_cast<const int4*>(bb + 8);
      *reinterpret_cast<int4*>(&Bs[sr * LDT + skc]) = p0;
      *reinterpret_cast<int4*>(&Bs[sr * LDT + skc + 8]) = p1;
    }
    __syncthreads();
#pragma unroll
    for (int kk = 0; kk < 2; ++kk) {
      const int ko = kk * 32 + (lane >> 4) * 8;
      short8 a0 = *reinterpret_cast<const short8*>(&As[(wm + (lane & 15)) * LDT + ko]);
      short8 a1 = *reinterpret_cast<const short8*>(&As[(wm + 16 + (lane & 15)) * LDT + ko]);
      short8 b0 = *reinterpret_cast<const short8*>(&Bs[(wn + (lane & 15)) * LDT + ko]);
      short8 b1 = *reinterpret_cast<const short8*>(&Bs[(wn + 16 + (lane & 15)) * LDT + ko]);
      acc[0][0] = __builtin_amdgcn_mfma_f32_16x16x32_bf16(a0, b0, acc[0][0], 0, 0, 0);
      acc[0][1] = __builtin_amdgcn_mfma_f32_16x16x32_bf16(a0, b1, acc[0][1], 0, 0, 0);
      acc[1][0] = __builtin_amdgcn_mfma_f32_16x16x32_bf16(a1, b0, acc[1][0], 0, 0, 0);
      acc[1][1] = __builtin_amdgcn_mfma_f32_16x16x32_bf16(a1, b1, acc[1][1], 0, 0, 0);
    }
    __syncthreads();
  }

#pragma unroll
  for (int mi = 0; mi < 2; ++mi)
#pragma unroll
    for (int ni = 0; ni < 2; ++ni) {
      int col = wn + ni * 16 + (lane & 15);
      int rowb = wm + mi * 16 + (lane >> 4) * 4;
#pragma unroll
      for (int j = 0; j < 4; ++j) Co[(rowb + j) * LDC + col] = acc[mi][ni][j];
    }
  __syncthreads();
  {
    int r = row0 + sr;
    if (r < nrows) {
      float v[16];
#pragma unroll
      for (int i = 0; i < 16; ++i) {
        v[i] = Co[sr * LDC + skc + i] + bias[n0 + skc + i];
        if (RELU) v[i] = fmaxf(v[i], 0.f);
      }
      if (OUT_BF16) {
        unsigned short* dst = (unsigned short*)outv + (size_t)r * ldo + n0 + skc;
        ushort8 o0, o1;
#pragma unroll
        for (int i = 0; i < 8; ++i) { o0[i] = f2bf(v[i]); o1[i] = f2bf(v[8 + i]); }
        *reinterpret_cast<ushort8*>(dst) = o0;
        *reinterpret_cast<ushort8*>(dst + 8) = o1;
      } else {
        float* dst = (float*)outv + (size_t)r * ldo + n0 + skc;
#pragma unroll
        for (int i = 0; i < 4; ++i) {
          float4 o = make_float4(v[4 * i], v[4 * i + 1], v[4 * i + 2], v[4 * i + 3]);
          *reinterpret_cast<float4*>(dst + 4 * i) = o;
        }
      }
    }
  }
}

// ---------------- BN ----------------
__global__ __launch_bounds__(256) void bn_stats_kernel(const float* __restrict__ x,
                                                       float* __restrict__ sums,
                                                       float* __restrict__ sumsq) {
  int c = threadIdx.x & 127;
  int rbase = (blockIdx.x * 256 + threadIdx.x) >> 7;
  int stride = (gridDim.x * 256) >> 7;
  float s = 0.f, s2 = 0.f;
  for (int r = rbase; r < NN; r += stride) {
    float v = x[(size_t)r * 128 + c];
    s += v;
    s2 += v * v;
  }
  __shared__ float ls[256], ls2[256];
  ls[threadIdx.x] = s;
  ls2[threadIdx.x] = s2;
  __syncthreads();
  if (threadIdx.x < 128) {
    s = ls[threadIdx.x] + ls[threadIdx.x + 128];
    s2 = ls2[threadIdx.x] + ls2[threadIdx.x + 128];
    atomicAdd(&sums[c], s);
    atomicAdd(&sumsq[c], s2);
  }
}

__global__ __launch_bounds__(128) void bn_finalize_kernel(float* __restrict__ stats,
                                                          const float* __restrict__ gamma,
                                                          const float* __restrict__ beta) {
  int c = threadIdx.x;
  float mu = stats[c] * (1.0f / NN);
  float var = stats[128 + c] * (1.0f / NN) - mu * mu;
  var = fmaxf(var, 0.f);
  float sc = gamma[c] * rsqrtf(var + BN_EPS);
  stats[256 + c] = sc;
  stats[384 + c] = beta[c] - mu * sc;
}

// ---------------- launch ----------------
extern "C" void kernel_launch(void* const* d_in, const int* in_sizes, int n_in,
                              void* d_out, int out_size, void* d_ws, size_t ws_size,
                              hipStream_t stream) {
  const float* feat = (const float*)d_in[0];
  const int* g_src = (const int*)d_in[1];
  const int* g_dst = (const int*)d_in[2];
  const int* k_src = (const int*)d_in[3];
  const int* k_dst = (const int*)d_in[4];
  const float* mlp_b1 = (const float*)d_in[21];
  const float* bn_gamma = (const float*)d_in[22];
  const float* bn_beta = (const float*)d_in[23];
  const float* mlp_b2 = (const float*)d_in[25];
  const float* lb_0 = (const float*)d_in[7];
  const float* lb_1 = (const float*)d_in[10];
  const float* lb_2 = (const float*)d_in[13];
  const float* gb_0 = (const float*)d_in[16];
  const float* gb_1 = (const float*)d_in[19];
  float* out = (float*)d_out;

  float* xf32 = (float*)d_ws;
  float* invg = xf32 + (size_t)NN * 128;
  float* invk = invg + NN;
  float* stats = invk + NN;
  unsigned short* bfA = (unsigned short*)(stats + 512);
  unsigned short* bfB = bfA + (size_t)NN * HF;
  unsigned short* bfAgg = bfB + (size_t)NN * HF;
  unsigned short* bfD = bfAgg + (size_t)NN * HF;
  unsigned short* featbf = bfD + (size_t)NN * HF;
  unsigned short* wts = featbf + (size_t)NN * IN_F;
  int* cnt_g = (int*)(wts + 598016);
  int* off_g = cnt_g + NN;
  int* esrc_g = off_g + NN + 1;
  int* cnt_k = esrc_g + EG;
  int* off_k = cnt_k + NN;
  int* esrc_k = off_k + NN + 1;
  int* part_g = esrc_k + EK;   // 256
  int* part_k = part_g + 256;  // 256

  const int wL0 = 0, wL1 = 65536, wL2 = 196608, wG0 = 327680, wG1 = 393216,
            wH1 = 524288, wH2 = 589824;

  dim3 blk(256);
  const dim3 gridH(4, (NN + 63) / 64);
  const dim3 gridM(2, (NN + 63) / 64);
  const dim3 gridO(1, (NN + 63) / 64);
  const int NB = (NN + 255) / 256;  // 196 scan blocks
  const int ngroups = (NN + 511) / 512;           // 64 groups * NPG=8
  const int agg128_blocks = ngroups * 4;          // NCHUNK=4
  const int agg256_blocks = ngroups * 8;          // NCHUNK=8

  cvt_bf16_kernel<<<(NN * IN_F / 8 + 255) / 256, blk, 0, stream>>>(feat, featbf, NN * IN_F / 8);
  {
    WPack p;
    p.d[0] = {(const float*)d_in[5], 128, 8, 0, 256, wL0};
    p.d[1] = {(const float*)d_in[6], 128, 8, 128, 256, wL0};
    p.d[2] = {(const float*)d_in[8], 256, 8, 0, 512, wL1};
    p.d[3] = {(const float*)d_in[9], 256, 8, 256, 512, wL1};
    p.d[4] = {(const float*)d_in[11], 256, 8, 0, 512, wL2};
    p.d[5] = {(const float*)d_in[12], 256, 8, 256, 512, wL2};
    p.d[6] = {(const float*)d_in[14], 128, 8, 0, 256, wG0};
    p.d[7] = {(const float*)d_in[15], 128, 8, 128, 256, wG0};
    p.d[8] = {(const float*)d_in[17], 256, 8, 0, 512, wG1};
    p.d[9] = {(const float*)d_in[18], 256, 8, 256, 512, wG1};
    p.d[10] = {(const float*)d_in[20], 512, 7, 0, 512, wH1};
    p.d[11] = {(const float*)d_in[24], 128, 6, 0, 128, wH2};
    transpose_weights_kernel<<<dim3(32, 12), blk, 0, stream>>>(p, wts);
  }

  // ---- CSR build ----
  hipMemsetAsync(cnt_g, 0, NN * sizeof(int), stream);
  hipMemsetAsync(cnt_k, 0, NN * sizeof(int), stream);
  count_kernel<<<(EG + 255) / 256, blk, 0, stream>>>(g_dst, EG, cnt_g);
  count_kernel<<<(EK + 255) / 256, blk, 0, stream>>>(k_dst, EK, cnt_k);
  invdeg_kernel<<<(NN + 255) / 256, blk, 0, stream>>>(cnt_g, invg);
  invdeg_kernel<<<(NN + 255) / 256, blk, 0, stream>>>(cnt_k, invk);
  scan_partial<<<NB, blk, 0, stream>>>(cnt_g, part_g, NN);
  scan_partial<<<NB, blk, 0, stream>>>(cnt_k, part_k, NN);
  scan_block<<<1, blk, 0, stream>>>(part_g, NB);
  scan_block<<<1, blk, 0, stream>>>(part_k, NB);
  scan_final<<<NB, blk, 0, stream>>>(cnt_g, part_g, off_g, NN, EG);
  scan_final<<<NB, blk, 0, stream>>>(cnt_k, part_k, off_k, NN, EK);
  hipMemsetAsync(cnt_g, 0, NN * sizeof(int), stream);
  hipMemsetAsync(cnt_k, 0, NN * sizeof(int), stream);
  fill_kernel<<<(EG + 255) / 256, blk, 0, stream>>>(g_src, g_dst, EG, off_g, cnt_g, esrc_g);
  fill_kernel<<<(EK + 255) / 256, blk, 0, stream>>>(k_src, k_dst, EK, off_k, cnt_k, esrc_k);

  // ---- local layer 0 ----
  csr_aggregate_chunk<7, 4, 8><<<agg128_blocks, blk, 0, stream>>>(featbf, off_g, esrc_g, invg, bfAgg);
  gemm_mfma<128, 128, true, false, true><<<gridH, blk, 0, stream>>>(
      featbf, bfAgg, wts + wL0, lb_0, nullptr, nullptr, bfA, HF, NN);
  // ---- local layer 1 ----
  csr_aggregate_chunk<8, 8, 8><<<agg256_blocks, blk, 0, stream>>>(bfA, off_g, esrc_g, invg, bfAgg);
  gemm_mfma<256, 256, true, false, true><<<gridH, blk, 0, stream>>>(
      bfA, bfAgg, wts + wL1, lb_1, nullptr, nullptr, bfB, HF, NN);
  // ---- local layer 2 -> local_emb ----
  csr_aggregate_chunk<8, 8, 8><<<agg256_blocks, blk, 0, stream>>>(bfB, off_g, esrc_g, invg, bfAgg);
  gemm_mfma<256, 256, false, false, true><<<gridH, blk, 0, stream>>>(
      bfB, bfAgg, wts + wL2, lb_2, nullptr, nullptr, bfD, HF, NN);
  // ---- global layer 0 ----
  csr_aggregate_chunk<7, 4, 8><<<agg128_blocks, blk, 0, stream>>>(featbf, off_k, esrc_k, invk, bfAgg);
  gemm_mfma<128, 128, true, false, true><<<gridH, blk, 0, stream>>>(
      featbf, bfAgg, wts + wG0, gb_0, nullptr, nullptr, bfA, HF, NN);
  // ---- global layer 1 -> global_emb ----
  csr_aggregate_chunk<8, 8, 8><<<agg256_blocks, blk, 0, stream>>>(bfA, off_k, esrc_k, invk, bfAgg);
  gemm_mfma<256, 256, false, false, true><<<gridH, blk, 0, stream>>>(
      bfA, bfAgg, wts + wG1, gb_1, nullptr, nullptr, bfB, HF, NN);

  // ---- head GEMM1 ----
  gemm_mfma<256, 256, false, false, false><<<gridM, blk, 0, stream>>>(
      bfD, bfB, wts + wH1, mlp_b1, nullptr, nullptr, xf32, MLPH, NN);

  // ---- BatchNorm ----
  hipMemsetAsync(stats, 0, 2 * 128 * sizeof(float), stream);
  bn_stats_kernel<<<256, blk, 0, stream>>>(xf32, stats, stats + 128);
  bn_finalize_kernel<<<1, 128, 0, stream>>>(stats, bn_gamma, bn_beta);

  // ---- head GEMM2 ----
  gemm_mfma<128, 0, false, true, false><<<gridO, blk, 0, stream>>>(
      xf32, nullptr, wts + wH2, mlp_b2, stats + 256, stats + 384, out, COUT, NN);
}

// Round 5
// 614.967 us; speedup vs baseline: 1.3405x; 1.3405x over previous
//
#include <hip/hip_runtime.h>

#define NN   50000
#define IN_F 128
#define HF   256
#define COUT 64
#define MLPH 128
#define EG   600000
#define EK   800000
#define BN_EPS 1e-5f

typedef __attribute__((ext_vector_type(8))) short short8;
typedef __attribute__((ext_vector_type(8))) unsigned short ushort8;
typedef __attribute__((ext_vector_type(4))) float f32x4;

__device__ __forceinline__ unsigned short f2bf(float f) {
  union { float f; unsigned int u; } v; v.f = f;
  unsigned int r = v.u + 0x7FFFu + ((v.u >> 16) & 1u);
  return (unsigned short)(r >> 16);
}
__device__ __forceinline__ float bf2f(unsigned short s) {
  union { unsigned int u; float f; } v; v.u = ((unsigned int)s) << 16;
  return v.f;
}

// ---------------- feat -> bf16 ----------------
__global__ __launch_bounds__(256) void cvt_bf16_kernel(const float* __restrict__ in,
                                                       unsigned short* __restrict__ out,
                                                       int n8) {
  int i = blockIdx.x * 256 + threadIdx.x;
  if (i < n8) {
    float4 a = *reinterpret_cast<const float4*>(&in[i * 8]);
    float4 b = *reinterpret_cast<const float4*>(&in[i * 8 + 4]);
    ushort8 o;
    o[0] = f2bf(a.x); o[1] = f2bf(a.y); o[2] = f2bf(a.z); o[3] = f2bf(a.w);
    o[4] = f2bf(b.x); o[5] = f2bf(b.y); o[6] = f2bf(b.z); o[7] = f2bf(b.w);
    *reinterpret_cast<ushort8*>(&out[i * 8]) = o;
  }
}

// ---------------- weight transpose+convert ----------------
struct WDesc { const float* src; int rows; int cshift; int kofs; int ldk; int dofs; };
struct WPack { WDesc d[12]; };

__global__ __launch_bounds__(256) void transpose_weights_kernel(WPack p,
                                                                unsigned short* __restrict__ dst) {
  WDesc w = p.d[blockIdx.y];
  int total = w.rows << w.cshift;
  int cmask = (1 << w.cshift) - 1;
  for (int idx = blockIdx.x * 256 + threadIdx.x; idx < total; idx += gridDim.x * 256) {
    int r = idx >> w.cshift;
    int c = idx & cmask;
    dst[w.dofs + (size_t)c * w.ldk + w.kofs + r] = f2bf(w.src[idx]);
  }
}

// ---------------- CSR build ----------------
__global__ __launch_bounds__(256) void count_kernel(const int* __restrict__ dst, int E,
                                                    int* __restrict__ cnt) {
  int e = blockIdx.x * 256 + threadIdx.x;
  if (e < E) atomicAdd(&cnt[dst[e]], 1);
}

__global__ __launch_bounds__(256) void invdeg_kernel(const int* __restrict__ cnt,
                                                     float* __restrict__ inv) {
  int i = blockIdx.x * 256 + threadIdx.x;
  if (i < NN) inv[i] = 1.0f / fmaxf((float)cnt[i], 1.0f);
}

// ---- parallel scan ----
__global__ __launch_bounds__(256) void scan_partial(const int* __restrict__ cnt,
                                                    int* __restrict__ part, int n) {
  int i = blockIdx.x * 256 + threadIdx.x;
  int v = (i < n) ? cnt[i] : 0;
  __shared__ int ws[4];
  int lane = threadIdx.x & 63, wid = threadIdx.x >> 6;
  int x = v;
#pragma unroll
  for (int d = 1; d < 64; d <<= 1) { int y = __shfl_up(x, d, 64); if (lane >= d) x += y; }
  if (lane == 63) ws[wid] = x;
  __syncthreads();
  if (threadIdx.x == 0) part[blockIdx.x] = ws[0] + ws[1] + ws[2] + ws[3];
}

__global__ __launch_bounds__(256) void scan_block(int* __restrict__ part, int np) {
  __shared__ int ws[4];
  int tid = threadIdx.x, lane = tid & 63, wid = tid >> 6;
  int v = (tid < np) ? part[tid] : 0;
  int x = v;
#pragma unroll
  for (int d = 1; d < 64; d <<= 1) { int y = __shfl_up(x, d, 64); if (lane >= d) x += y; }
  if (lane == 63) ws[wid] = x;
  __syncthreads();
  int add = 0;
#pragma unroll
  for (int k = 0; k < 4; ++k) if (k < wid) add += ws[k];
  if (tid < np) part[tid] = x - v + add;
}

__global__ __launch_bounds__(256) void scan_final(const int* __restrict__ cnt,
                                                  const int* __restrict__ part,
                                                  int* __restrict__ off, int n, int total) {
  int i = blockIdx.x * 256 + threadIdx.x;
  int v = (i < n) ? cnt[i] : 0;
  __shared__ int ws[4];
  int lane = threadIdx.x & 63, wid = threadIdx.x >> 6;
  int x = v;
#pragma unroll
  for (int d = 1; d < 64; d <<= 1) { int y = __shfl_up(x, d, 64); if (lane >= d) x += y; }
  if (lane == 63) ws[wid] = x;
  __syncthreads();
  int add = part[blockIdx.x];
#pragma unroll
  for (int k = 0; k < 4; ++k) if (k < wid) add += ws[k];
  if (i < n) off[i] = x - v + add;
  if (i == 0) off[n] = total;
}

__global__ __launch_bounds__(256) void fill_kernel(const int* __restrict__ src,
                                                   const int* __restrict__ dst, int E,
                                                   const int* __restrict__ off,
                                                   int* __restrict__ cursor,
                                                   int* __restrict__ esrc) {
  int e = blockIdx.x * 256 + threadIdx.x;
  if (e < E) {
    int d = dst[e];
    int p = atomicAdd(&cursor[d], 1);
    esrc[off[d] + p] = src[e];
  }
}

// ---------------- CSR mean-aggregation (bf16 in/out), unroll-4 ----------------
template <int DLOG2>
__global__ __launch_bounds__(256) void csr_aggregate(const unsigned short* __restrict__ h,
                                                     const int* __restrict__ off,
                                                     const int* __restrict__ esrc,
                                                     const float* __restrict__ inv,
                                                     unsigned short* __restrict__ out) {
  constexpr int TPN = (1 << DLOG2) / 8;  // lanes per node, 8 bf16 (16B) each
  constexpr int NPB = 256 / TPN;
  int node = blockIdx.x * NPB + (threadIdx.x / TPN);
  int lane = threadIdx.x & (TPN - 1);
  if (node >= NN) return;
  int s = off[node], e = off[node + 1];
  float acc[8] = {0.f, 0.f, 0.f, 0.f, 0.f, 0.f, 0.f, 0.f};
  int j = s;
  for (; j + 3 < e; j += 4) {
    int s0 = esrc[j], s1 = esrc[j + 1], s2 = esrc[j + 2], s3 = esrc[j + 3];
    ushort8 v0 = *reinterpret_cast<const ushort8*>(&h[((size_t)s0 << DLOG2) + lane * 8]);
    ushort8 v1 = *reinterpret_cast<const ushort8*>(&h[((size_t)s1 << DLOG2) + lane * 8]);
    ushort8 v2 = *reinterpret_cast<const ushort8*>(&h[((size_t)s2 << DLOG2) + lane * 8]);
    ushort8 v3 = *reinterpret_cast<const ushort8*>(&h[((size_t)s3 << DLOG2) + lane * 8]);
#pragma unroll
    for (int i = 0; i < 8; ++i) acc[i] += bf2f(v0[i]);
#pragma unroll
    for (int i = 0; i < 8; ++i) acc[i] += bf2f(v1[i]);
#pragma unroll
    for (int i = 0; i < 8; ++i) acc[i] += bf2f(v2[i]);
#pragma unroll
    for (int i = 0; i < 8; ++i) acc[i] += bf2f(v3[i]);
  }
  for (; j < e; ++j) {
    int s0 = esrc[j];
    ushort8 v0 = *reinterpret_cast<const ushort8*>(&h[((size_t)s0 << DLOG2) + lane * 8]);
#pragma unroll
    for (int i = 0; i < 8; ++i) acc[i] += bf2f(v0[i]);
  }
  float sc = inv[node];
  ushort8 o;
#pragma unroll
  for (int i = 0; i < 8; ++i) o[i] = f2bf(acc[i] * sc);
  *reinterpret_cast<ushort8*>(&out[((size_t)node << DLOG2) + lane * 8]) = o;
}

// ---------------- MFMA GEMM, BM=128 x BN=64, BK=64, 4 waves ----------------
// out[m][n] = act( sum_{k<K1} A1[m][k] Bt[n][k] + sum_{k<K2} A2[m][k] Bt[n][K1+k] + bias[n] )
template <int K1, int K2, bool RELU, bool OUT_BF16>
__global__ __launch_bounds__(256) void gemm_mfma128(
    const unsigned short* __restrict__ A1, const unsigned short* __restrict__ A2,
    const unsigned short* __restrict__ Bt, const float* __restrict__ bias,
    void* __restrict__ outv, int ldo, int nrows) {
  constexpr int KTOT = K1 + K2;
  constexpr int KT = KTOT / 64;
  constexpr int LDT = 72;  // bf16 units; 144B row stride
  constexpr int LDC = 68;
  __shared__ char smem[128 * LDC * 4];  // 34816B >= (128+64)*LDT*2 = 27648B
  unsigned short* As = (unsigned short*)smem;          // [128][LDT]
  unsigned short* Bs = As + 128 * LDT;                 // [64][LDT]
  float* Co = (float*)smem;                            // [128][LDC] epilogue

  const int t = threadIdx.x;
  const int lane = t & 63;
  const int w = t >> 6;
  const int wm = w * 32;
  const int row0 = blockIdx.y * 128;
  const int n0 = blockIdx.x * 64;

  // staging maps
  const int arow = t >> 1, akb = (t & 1) * 32;   // A: 4 x int4 per thread
  const int brow = t >> 2, bkb = (t & 3) * 16;   // B: 2 x int4 per thread
  int rg = row0 + arow;
  if (rg >= nrows) rg = nrows - 1;

  f32x4 acc[2][4] = {};

  for (int kt = 0; kt < KT; ++kt) {
    const int kbase = kt * 64;
    const unsigned short* ab = (kbase < K1)
        ? (A1 + (size_t)rg * K1 + kbase + akb)
        : (A2 + (size_t)rg * K2 + (kbase - K1) + akb);
#pragma unroll
    for (int c = 0; c < 4; ++c) {
      int4 p = *reinterpret_cast<const int4*>(ab + c * 8);
      *reinterpret_cast<int4*>(&As[arow * LDT + akb + c * 8]) = p;
    }
    {
      const unsigned short* bb = Bt + (size_t)(n0 + brow) * KTOT + kbase + bkb;
      int4 p0 = *reinterpret_cast<const int4*>(bb);
      int4 p1 = *reinterpret_cast<const int4*>(bb + 8);
      *reinterpret_cast<int4*>(&Bs[brow * LDT + bkb]) = p0;
      *reinterpret_cast<int4*>(&Bs[brow * LDT + bkb + 8]) = p1;
    }
    __syncthreads();
#pragma unroll
    for (int kk = 0; kk < 2; ++kk) {
      const int ko = kk * 32 + (lane >> 4) * 8;
      short8 a0 = *reinterpret_cast<const short8*>(&As[(wm + (lane & 15)) * LDT + ko]);
      short8 a1 = *reinterpret_cast<const short8*>(&As[(wm + 16 + (lane & 15)) * LDT + ko]);
      short8 b0 = *reinterpret_cast<const short8*>(&Bs[((lane & 15)) * LDT + ko]);
      short8 b1 = *reinterpret_cast<const short8*>(&Bs[(16 + (lane & 15)) * LDT + ko]);
      short8 b2 = *reinterpret_cast<const short8*>(&Bs[(32 + (lane & 15)) * LDT + ko]);
      short8 b3 = *reinterpret_cast<const short8*>(&Bs[(48 + (lane & 15)) * LDT + ko]);
      acc[0][0] = __builtin_amdgcn_mfma_f32_16x16x32_bf16(a0, b0, acc[0][0], 0, 0, 0);
      acc[0][1] = __builtin_amdgcn_mfma_f32_16x16x32_bf16(a0, b1, acc[0][1], 0, 0, 0);
      acc[0][2] = __builtin_amdgcn_mfma_f32_16x16x32_bf16(a0, b2, acc[0][2], 0, 0, 0);
      acc[0][3] = __builtin_amdgcn_mfma_f32_16x16x32_bf16(a0, b3, acc[0][3], 0, 0, 0);
      acc[1][0] = __builtin_amdgcn_mfma_f32_16x16x32_bf16(a1, b0, acc[1][0], 0, 0, 0);
      acc[1][1] = __builtin_amdgcn_mfma_f32_16x16x32_bf16(a1, b1, acc[1][1], 0, 0, 0);
      acc[1][2] = __builtin_amdgcn_mfma_f32_16x16x32_bf16(a1, b2, acc[1][2], 0, 0, 0);
      acc[1][3] = __builtin_amdgcn_mfma_f32_16x16x32_bf16(a1, b3, acc[1][3], 0, 0, 0);
    }
    __syncthreads();
  }

  // ---- epilogue via LDS for coalesced stores ----
#pragma unroll
  for (int mi = 0; mi < 2; ++mi)
#pragma unroll
    for (int ni = 0; ni < 4; ++ni) {
      int col = ni * 16 + (lane & 15);
      int rowb = wm + mi * 16 + (lane >> 4) * 4;
#pragma unroll
      for (int j = 0; j < 4; ++j) Co[(rowb + j) * LDC + col] = acc[mi][ni][j];
    }
  __syncthreads();
  {
    const int sr = t >> 1, cb = (t & 1) * 32;
    int r = row0 + sr;
    if (r < nrows) {
      float v[32];
#pragma unroll
      for (int i = 0; i < 32; ++i) {
        v[i] = Co[sr * LDC + cb + i] + bias[n0 + cb + i];
        if (RELU) v[i] = fmaxf(v[i], 0.f);
      }
      if (OUT_BF16) {
        unsigned short* dst = (unsigned short*)outv + (size_t)r * ldo + n0 + cb;
#pragma unroll
        for (int q = 0; q < 4; ++q) {
          ushort8 o;
#pragma unroll
          for (int i = 0; i < 8; ++i) o[i] = f2bf(v[q * 8 + i]);
          *reinterpret_cast<ushort8*>(dst + q * 8) = o;
        }
      } else {
        float* dst = (float*)outv + (size_t)r * ldo + n0 + cb;
#pragma unroll
        for (int q = 0; q < 8; ++q) {
          float4 o = make_float4(v[4 * q], v[4 * q + 1], v[4 * q + 2], v[4 * q + 3]);
          *reinterpret_cast<float4*>(dst + 4 * q) = o;
        }
      }
    }
  }
}

// ---------------- MFMA GEMM 64x64 (BN1 head only) ----------------
template <int K1, bool RELU>
__global__ __launch_bounds__(256) void gemm_mfma_bn(
    const float* __restrict__ A1v, const unsigned short* __restrict__ Bt,
    const float* __restrict__ bias, const float* __restrict__ bnscale,
    const float* __restrict__ bnshift, float* __restrict__ outv, int ldo, int nrows) {
  constexpr int KTOT = K1;
  constexpr int KT = KTOT / 64;
  constexpr int LDT = 72;
  __shared__ char smem[2 * 64 * LDT * 2];
  unsigned short* As = (unsigned short*)smem;
  unsigned short* Bs = As + 64 * LDT;
  float* Co = (float*)smem;
  constexpr int LDC = 68;

  const int t = threadIdx.x;
  const int lane = t & 63;
  const int w = t >> 6;
  const int wm = (w & 1) * 32, wn = (w >> 1) * 32;
  const int row0 = blockIdx.y * 64;
  const int n0 = blockIdx.x * 64;

  const int sr = t >> 2;
  const int skc = (t & 3) * 16;
  int rg = row0 + sr;
  if (rg >= nrows) rg = nrows - 1;

  f32x4 acc[2][2] = {};

  for (int kt = 0; kt < KT; ++kt) {
    const int kbase = kt * 64;
    {
      const float* xb = A1v + (size_t)rg * K1 + kbase + skc;
      ushort8 o0, o1;
#pragma unroll
      for (int i = 0; i < 8; ++i) {
        float v = xb[i] * bnscale[kbase + skc + i] + bnshift[kbase + skc + i];
        o0[i] = f2bf(fmaxf(v, 0.f));
      }
#pragma unroll
      for (int i = 0; i < 8; ++i) {
        float v = xb[8 + i] * bnscale[kbase + skc + 8 + i] + bnshift[kbase + skc + 8 + i];
        o1[i] = f2bf(fmaxf(v, 0.f));
      }
      *reinterpret_cast<ushort8*>(&As[sr * LDT + skc]) = o0;
      *reinterpret_cast<ushort8*>(&As[sr * LDT + skc + 8]) = o1;
    }
    {
      const unsigned short* bb = Bt + (size_t)(n0 + sr) * KTOT + kbase + skc;
      int4 p0 = *reinterpret_cast<const int4*>(bb);
      int4 p1 = *reinterpret_cast<const int4*>(bb + 8);
      *reinterpret_cast<int4*>(&Bs[sr * LDT + skc]) = p0;
      *reinterpret_cast<int4*>(&Bs[sr * LDT + skc + 8]) = p1;
    }
    __syncthreads();
#pragma unroll
    for (int kk = 0; kk < 2; ++kk) {
      const int ko = kk * 32 + (lane >> 4) * 8;
      short8 a0 = *reinterpret_cast<const short8*>(&As[(wm + (lane & 15)) * LDT + ko]);
      short8 a1 = *reinterpret_cast<const short8*>(&As[(wm + 16 + (lane & 15)) * LDT + ko]);
      short8 b0 = *reinterpret_cast<const short8*>(&Bs[(wn + (lane & 15)) * LDT + ko]);
      short8 b1 = *reinterpret_cast<const short8*>(&Bs[(wn + 16 + (lane & 15)) * LDT + ko]);
      acc[0][0] = __builtin_amdgcn_mfma_f32_16x16x32_bf16(a0, b0, acc[0][0], 0, 0, 0);
      acc[0][1] = __builtin_amdgcn_mfma_f32_16x16x32_bf16(a0, b1, acc[0][1], 0, 0, 0);
      acc[1][0] = __builtin_amdgcn_mfma_f32_16x16x32_bf16(a1, b0, acc[1][0], 0, 0, 0);
      acc[1][1] = __builtin_amdgcn_mfma_f32_16x16x32_bf16(a1, b1, acc[1][1], 0, 0, 0);
    }
    __syncthreads();
  }

#pragma unroll
  for (int mi = 0; mi < 2; ++mi)
#pragma unroll
    for (int ni = 0; ni < 2; ++ni) {
      int col = wn + ni * 16 + (lane & 15);
      int rowb = wm + mi * 16 + (lane >> 4) * 4;
#pragma unroll
      for (int j = 0; j < 4; ++j) Co[(rowb + j) * LDC + col] = acc[mi][ni][j];
    }
  __syncthreads();
  {
    int r = row0 + sr;
    if (r < nrows) {
      float v[16];
#pragma unroll
      for (int i = 0; i < 16; ++i) {
        v[i] = Co[sr * LDC + skc + i] + bias[n0 + skc + i];
        if (RELU) v[i] = fmaxf(v[i], 0.f);
      }
      float* dst = outv + (size_t)r * ldo + n0 + skc;
#pragma unroll
      for (int i = 0; i < 4; ++i) {
        float4 o = make_float4(v[4 * i], v[4 * i + 1], v[4 * i + 2], v[4 * i + 3]);
        *reinterpret_cast<float4*>(dst + 4 * i) = o;
      }
    }
  }
}

// ---------------- BN ----------------
__global__ __launch_bounds__(256) void bn_stats_kernel(const float* __restrict__ x,
                                                       float* __restrict__ sums,
                                                       float* __restrict__ sumsq) {
  int c = threadIdx.x & 127;
  int rbase = (blockIdx.x * 256 + threadIdx.x) >> 7;
  int stride = (gridDim.x * 256) >> 7;
  float s = 0.f, s2 = 0.f;
  for (int r = rbase; r < NN; r += stride) {
    float v = x[(size_t)r * 128 + c];
    s += v;
    s2 += v * v;
  }
  __shared__ float ls[256], ls2[256];
  ls[threadIdx.x] = s;
  ls2[threadIdx.x] = s2;
  __syncthreads();
  if (threadIdx.x < 128) {
    s = ls[threadIdx.x] + ls[threadIdx.x + 128];
    s2 = ls2[threadIdx.x] + ls2[threadIdx.x + 128];
    atomicAdd(&sums[c], s);
    atomicAdd(&sumsq[c], s2);
  }
}

__global__ __launch_bounds__(128) void bn_finalize_kernel(float* __restrict__ stats,
                                                          const float* __restrict__ gamma,
                                                          const float* __restrict__ beta) {
  int c = threadIdx.x;
  float mu = stats[c] * (1.0f / NN);
  float var = stats[128 + c] * (1.0f / NN) - mu * mu;
  var = fmaxf(var, 0.f);
  float sc = gamma[c] * rsqrtf(var + BN_EPS);
  stats[256 + c] = sc;
  stats[384 + c] = beta[c] - mu * sc;
}

// ---------------- launch ----------------
extern "C" void kernel_launch(void* const* d_in, const int* in_sizes, int n_in,
                              void* d_out, int out_size, void* d_ws, size_t ws_size,
                              hipStream_t stream) {
  const float* feat = (const float*)d_in[0];
  const int* g_src = (const int*)d_in[1];
  const int* g_dst = (const int*)d_in[2];
  const int* k_src = (const int*)d_in[3];
  const int* k_dst = (const int*)d_in[4];
  const float* mlp_b1 = (const float*)d_in[21];
  const float* bn_gamma = (const float*)d_in[22];
  const float* bn_beta = (const float*)d_in[23];
  const float* mlp_b2 = (const float*)d_in[25];
  const float* lb_0 = (const float*)d_in[7];
  const float* lb_1 = (const float*)d_in[10];
  const float* lb_2 = (const float*)d_in[13];
  const float* gb_0 = (const float*)d_in[16];
  const float* gb_1 = (const float*)d_in[19];
  float* out = (float*)d_out;

  float* xf32 = (float*)d_ws;
  float* invg = xf32 + (size_t)NN * 128;
  float* invk = invg + NN;
  float* stats = invk + NN;
  unsigned short* bfA = (unsigned short*)(stats + 512);
  unsigned short* bfB = bfA + (size_t)NN * HF;
  unsigned short* bfAgg = bfB + (size_t)NN * HF;
  unsigned short* bfD = bfAgg + (size_t)NN * HF;
  unsigned short* featbf = bfD + (size_t)NN * HF;
  unsigned short* wts = featbf + (size_t)NN * IN_F;
  int* cnt_g = (int*)(wts + 598016);
  int* off_g = cnt_g + NN;
  int* esrc_g = off_g + NN + 1;
  int* cnt_k = esrc_g + EG;
  int* off_k = cnt_k + NN;
  int* esrc_k = off_k + NN + 1;
  int* part_g = esrc_k + EK;   // 256
  int* part_k = part_g + 256;  // 256

  const int wL0 = 0, wL1 = 65536, wL2 = 196608, wG0 = 327680, wG1 = 393216,
            wH1 = 524288, wH2 = 589824;

  dim3 blk(256);
  const int MB = (NN + 127) / 128;  // 391
  const dim3 gridH(4, MB);          // 256-col out, BM=128
  const dim3 gridM(2, MB);          // 128-col out
  const dim3 gridO(1, (NN + 63) / 64);  // 64-col out (old kernel)
  const int NB = (NN + 255) / 256;  // 196 scan blocks
  const int agg128_blocks = (NN + 15) / 16;  // TPN=16
  const int agg256_blocks = (NN + 7) / 8;    // TPN=32

  cvt_bf16_kernel<<<(NN * IN_F / 8 + 255) / 256, blk, 0, stream>>>(feat, featbf, NN * IN_F / 8);
  {
    WPack p;
    p.d[0] = {(const float*)d_in[5], 128, 8, 0, 256, wL0};
    p.d[1] = {(const float*)d_in[6], 128, 8, 128, 256, wL0};
    p.d[2] = {(const float*)d_in[8], 256, 8, 0, 512, wL1};
    p.d[3] = {(const float*)d_in[9], 256, 8, 256, 512, wL1};
    p.d[4] = {(const float*)d_in[11], 256, 8, 0, 512, wL2};
    p.d[5] = {(const float*)d_in[12], 256, 8, 256, 512, wL2};
    p.d[6] = {(const float*)d_in[14], 128, 8, 0, 256, wG0};
    p.d[7] = {(const float*)d_in[15], 128, 8, 128, 256, wG0};
    p.d[8] = {(const float*)d_in[17], 256, 8, 0, 512, wG1};
    p.d[9] = {(const float*)d_in[18], 256, 8, 256, 512, wG1};
    p.d[10] = {(const float*)d_in[20], 512, 7, 0, 512, wH1};
    p.d[11] = {(const float*)d_in[24], 128, 6, 0, 128, wH2};
    transpose_weights_kernel<<<dim3(32, 12), blk, 0, stream>>>(p, wts);
  }

  // ---- CSR build ----
  hipMemsetAsync(cnt_g, 0, NN * sizeof(int), stream);
  hipMemsetAsync(cnt_k, 0, NN * sizeof(int), stream);
  count_kernel<<<(EG + 255) / 256, blk, 0, stream>>>(g_dst, EG, cnt_g);
  count_kernel<<<(EK + 255) / 256, blk, 0, stream>>>(k_dst, EK, cnt_k);
  invdeg_kernel<<<(NN + 255) / 256, blk, 0, stream>>>(cnt_g, invg);
  invdeg_kernel<<<(NN + 255) / 256, blk, 0, stream>>>(cnt_k, invk);
  scan_partial<<<NB, blk, 0, stream>>>(cnt_g, part_g, NN);
  scan_partial<<<NB, blk, 0, stream>>>(cnt_k, part_k, NN);
  scan_block<<<1, blk, 0, stream>>>(part_g, NB);
  scan_block<<<1, blk, 0, stream>>>(part_k, NB);
  scan_final<<<NB, blk, 0, stream>>>(cnt_g, part_g, off_g, NN, EG);
  scan_final<<<NB, blk, 0, stream>>>(cnt_k, part_k, off_k, NN, EK);
  hipMemsetAsync(cnt_g, 0, NN * sizeof(int), stream);
  hipMemsetAsync(cnt_k, 0, NN * sizeof(int), stream);
  fill_kernel<<<(EG + 255) / 256, blk, 0, stream>>>(g_src, g_dst, EG, off_g, cnt_g, esrc_g);
  fill_kernel<<<(EK + 255) / 256, blk, 0, stream>>>(k_src, k_dst, EK, off_k, cnt_k, esrc_k);

  // ---- local layer 0 ----
  csr_aggregate<7><<<agg128_blocks, blk, 0, stream>>>(featbf, off_g, esrc_g, invg, bfAgg);
  gemm_mfma128<128, 128, true, true><<<gridH, blk, 0, stream>>>(
      featbf, bfAgg, wts + wL0, lb_0, bfA, HF, NN);
  // ---- local layer 1 ----
  csr_aggregate<8><<<agg256_blocks, blk, 0, stream>>>(bfA, off_g, esrc_g, invg, bfAgg);
  gemm_mfma128<256, 256, true, true><<<gridH, blk, 0, stream>>>(
      bfA, bfAgg, wts + wL1, lb_1, bfB, HF, NN);
  // ---- local layer 2 -> local_emb ----
  csr_aggregate<8><<<agg256_blocks, blk, 0, stream>>>(bfB, off_g, esrc_g, invg, bfAgg);
  gemm_mfma128<256, 256, false, true><<<gridH, blk, 0, stream>>>(
      bfB, bfAgg, wts + wL2, lb_2, bfD, HF, NN);
  // ---- global layer 0 ----
  csr_aggregate<7><<<agg128_blocks, blk, 0, stream>>>(featbf, off_k, esrc_k, invk, bfAgg);
  gemm_mfma128<128, 128, true, true><<<gridH, blk, 0, stream>>>(
      featbf, bfAgg, wts + wG0, gb_0, bfA, HF, NN);
  // ---- global layer 1 -> global_emb ----
  csr_aggregate<8><<<agg256_blocks, blk, 0, stream>>>(bfA, off_k, esrc_k, invk, bfAgg);
  gemm_mfma128<256, 256, false, true><<<gridH, blk, 0, stream>>>(
      bfA, bfAgg, wts + wG1, gb_1, bfB, HF, NN);

  // ---- head GEMM1 ----
  gemm_mfma128<256, 256, false, false><<<gridM, blk, 0, stream>>>(
      bfD, bfB, wts + wH1, mlp_b1, xf32, MLPH, NN);

  // ---- BatchNorm ----
  hipMemsetAsync(stats, 0, 2 * 128 * sizeof(float), stream);
  bn_stats_kernel<<<256, blk, 0, stream>>>(xf32, stats, stats + 128);
  bn_finalize_kernel<<<1, 128, 0, stream>>>(stats, bn_gamma, bn_beta);

  // ---- head GEMM2 ----
  gemm_mfma_bn<128, false><<<gridO, blk, 0, stream>>>(
      xf32, wts + wH2, mlp_b2, stats + 256, stats + 384, out, COUT, NN);
}